// Round 3
// baseline (651.901 us; speedup 1.0000x reference)
//
#include <hip/hip_runtime.h>

// ---------------- CSR construction ----------------

__global__ __launch_bounds__(256) void hist_kernel(const int* __restrict__ dst,
                                                   int* __restrict__ deg, int nE) {
  int i = blockIdx.x * 256 + threadIdx.x;
  int stride = gridDim.x * 256;
  for (; i < nE; i += stride) atomicAdd(&deg[dst[i]], 1);
}

__global__ __launch_bounds__(256) void scan1(const int* __restrict__ deg,
                                             int* __restrict__ row_off,
                                             int* __restrict__ blocksums, int n) {
  __shared__ int s[256];
  int t = threadIdx.x, i = blockIdx.x * 256 + t;
  int v = (i < n) ? deg[i] : 0;
  s[t] = v;
  __syncthreads();
  for (int off = 1; off < 256; off <<= 1) {
    int x = (t >= off) ? s[t - off] : 0;
    __syncthreads();
    s[t] += x;
    __syncthreads();
  }
  if (i < n) row_off[i] = s[t] - v;        // local exclusive scan
  if (t == 255) blocksums[blockIdx.x] = s[t];
}

__global__ __launch_bounds__(512) void scan2(int* __restrict__ blocksums, int nb,
                                             int* __restrict__ total_out) {
  __shared__ int s[512];
  int t = threadIdx.x;
  int v = (t < nb) ? blocksums[t] : 0;
  s[t] = v;
  __syncthreads();
  for (int off = 1; off < 512; off <<= 1) {
    int x = (t >= off) ? s[t - off] : 0;
    __syncthreads();
    s[t] += x;
    __syncthreads();
  }
  if (t < nb) blocksums[t] = s[t] - v;     // exclusive block offsets
  if (t == 511) *total_out = s[511];       // row_off[N] = nE
}

__global__ __launch_bounds__(256) void scan3_dinv(int* __restrict__ row_off,
                                                  const int* __restrict__ blockoff,
                                                  const int* __restrict__ deg,
                                                  float* __restrict__ dinv, int n) {
  int i = blockIdx.x * 256 + threadIdx.x;
  if (i < n) {
    row_off[i] += blockoff[i >> 8];
    dinv[i] = rsqrtf((float)deg[i] + 1.0f);
  }
}

__global__ __launch_bounds__(256) void scatter_kernel(const int* __restrict__ src,
                                                      const int* __restrict__ dst,
                                                      const int* __restrict__ row_off,
                                                      int* __restrict__ cursor,
                                                      int* __restrict__ edge_src, int nE) {
  int i = blockIdx.x * 256 + threadIdx.x;
  int stride = gridDim.x * 256;
  for (; i < nE; i += stride) {
    int d = dst[i];
    int pos = row_off[d] + atomicAdd(&cursor[d], 1);
    edge_src[pos] = src[i];
  }
}

// ---------------- fp32 GEMM, K=128 fixed ----------------
template <int COLS, bool BIAS, bool RELU>
__global__ __launch_bounds__(256) void gemm_k128(const float* __restrict__ X,
                                                 const float* __restrict__ W,
                                                 const float* __restrict__ bias,
                                                 float* __restrict__ Y, int nrows) {
  constexpr int TN = COLS / 16;  // 8 (COLS=128) or 4 (COLS=64)
  __shared__ float Xs[128][33];
  __shared__ float Ws[32 * COLS];
  int tid = threadIdx.x;
  int ty = tid >> 4, tx = tid & 15;
  long row0 = (long)blockIdx.x * 128;

  float acc[8][TN];
#pragma unroll
  for (int r = 0; r < 8; ++r)
#pragma unroll
    for (int j = 0; j < TN; ++j) acc[r][j] = 0.f;

  for (int kt = 0; kt < 4; ++kt) {
#pragma unroll
    for (int l = 0; l < 4; ++l) {
      int idx = tid + l * 256;   // 0..1023 float4 slots
      int r = idx >> 3;          // row in tile
      int k4 = (idx & 7) << 2;   // k offset 0..28
      float4 v = make_float4(0.f, 0.f, 0.f, 0.f);
      long gr = row0 + r;
      if (gr < nrows) v = *(const float4*)(X + gr * 128 + kt * 32 + k4);
      Xs[r][k4 + 0] = v.x;
      Xs[r][k4 + 1] = v.y;
      Xs[r][k4 + 2] = v.z;
      Xs[r][k4 + 3] = v.w;
    }
    constexpr int WF4 = 32 * COLS / 4;
#pragma unroll
    for (int l = 0; l < WF4 / 256; ++l) {
      int idx = tid + l * 256;
      float4 v = *(const float4*)(W + (size_t)kt * 32 * COLS + (size_t)idx * 4);
      *(float4*)(&Ws[idx * 4]) = v;
    }
    __syncthreads();
#pragma unroll
    for (int kk = 0; kk < 32; ++kk) {
      float a[8];
#pragma unroll
      for (int r = 0; r < 8; ++r) a[r] = Xs[ty * 8 + r][kk];
      float b[TN];
      float4 b0 = *(const float4*)(&Ws[kk * COLS + tx * 4]);
      b[0] = b0.x; b[1] = b0.y; b[2] = b0.z; b[3] = b0.w;
      if constexpr (TN == 8) {
        float4 b1 = *(const float4*)(&Ws[kk * COLS + 64 + tx * 4]);
        b[4] = b1.x; b[5] = b1.y; b[6] = b1.z; b[7] = b1.w;
      }
#pragma unroll
      for (int r = 0; r < 8; ++r)
#pragma unroll
        for (int j = 0; j < TN; ++j) acc[r][j] = fmaf(a[r], b[j], acc[r][j]);
    }
    __syncthreads();
  }

  float bv[TN];
  if constexpr (BIAS) {
#pragma unroll
    for (int j = 0; j < TN; ++j) {
      int col = (j < 4) ? tx * 4 + j : 64 + tx * 4 + (j - 4);
      bv[j] = bias[col];
    }
  }
#pragma unroll
  for (int r = 0; r < 8; ++r) {
    long row = row0 + ty * 8 + r;
    if (row < nrows) {
      float4 o;
      o.x = acc[r][0]; o.y = acc[r][1]; o.z = acc[r][2]; o.w = acc[r][3];
      if constexpr (BIAS) { o.x += bv[0]; o.y += bv[1]; o.z += bv[2]; o.w += bv[3]; }
      if constexpr (RELU) {
        o.x = fmaxf(o.x, 0.f); o.y = fmaxf(o.y, 0.f);
        o.z = fmaxf(o.z, 0.f); o.w = fmaxf(o.w, 0.f);
      }
      *(float4*)(Y + row * COLS + tx * 4) = o;
      if constexpr (TN == 8) {
        float4 o2;
        o2.x = acc[r][4]; o2.y = acc[r][5]; o2.z = acc[r][6]; o2.w = acc[r][7];
        if constexpr (BIAS) { o2.x += bv[4]; o2.y += bv[5]; o2.z += bv[6]; o2.w += bv[7]; }
        if constexpr (RELU) {
          o2.x = fmaxf(o2.x, 0.f); o2.y = fmaxf(o2.y, 0.f);
          o2.z = fmaxf(o2.z, 0.f); o2.w = fmaxf(o2.w, 0.f);
        }
        *(float4*)(Y + row * COLS + 64 + tx * 4) = o2;
      }
    }
  }
}

// ---------------- neighbor aggregation (one node per block) ----------------
// 128 threads = 4 edge-groups x 32 feature-lanes (float4 each -> 128 feats).
// out[i][:] = relu( sum_e H[src_e]*dinv[src]*dinv[i] + H[i]*dinv[i]^2 + b )
__global__ __launch_bounds__(128) void agg_kernel(const float* __restrict__ H,
                                                  const int* __restrict__ row_off,
                                                  const int* __restrict__ edge_src,
                                                  const float* __restrict__ dinv,
                                                  const float* __restrict__ bias,
                                                  float* __restrict__ Out, int n) {
  int i = blockIdx.x;
  int t = threadIdx.x;
  int g = t >> 5;        // edge group 0..3
  int c = t & 31;        // feature slot: floats [4c, 4c+4)
  float di = dinv[i];
  int beg = row_off[i], end = row_off[i + 1];

  float4 acc = make_float4(0.f, 0.f, 0.f, 0.f);
  __shared__ int sidx[128];
  __shared__ float swt[128];
  for (int base = beg; base < end; base += 128) {
    int cnt = min(128, end - base);
    if (t < cnt) {
      int s = edge_src[base + t];
      sidx[t] = s;
      swt[t] = dinv[s] * di;
    }
    __syncthreads();
#pragma unroll 2
    for (int j = g; j < cnt; j += 4) {
      float4 v = *(const float4*)(H + (size_t)sidx[j] * 128 + c * 4);
      float w = swt[j];
      acc.x = fmaf(v.x, w, acc.x);
      acc.y = fmaf(v.y, w, acc.y);
      acc.z = fmaf(v.z, w, acc.z);
      acc.w = fmaf(v.w, w, acc.w);
    }
    __syncthreads();
  }

  // combine group pairs within each wave: lane l += lane l+32
  acc.x += __shfl_down(acc.x, 32);
  acc.y += __shfl_down(acc.y, 32);
  acc.z += __shfl_down(acc.z, 32);
  acc.w += __shfl_down(acc.w, 32);

  __shared__ float4 red[32];
  if (t >= 64 && (t & 63) < 32) red[c] = acc;   // wave 1 partial (groups 2+3)
  __syncthreads();
  if (t < 32) {
    float4 o = acc;
    float4 p = red[c];
    o.x += p.x; o.y += p.y; o.z += p.z; o.w += p.w;
    float4 h = *(const float4*)(H + (size_t)i * 128 + c * 4);
    float sw = di * di;
    float4 b = *(const float4*)(bias + c * 4);
    o.x = fmaxf(fmaf(h.x, sw, o.x) + b.x, 0.f);
    o.y = fmaxf(fmaf(h.y, sw, o.y) + b.y, 0.f);
    o.z = fmaxf(fmaf(h.z, sw, o.z) + b.z, 0.f);
    o.w = fmaxf(fmaf(h.w, sw, o.w) + b.w, 0.f);
    *(float4*)(Out + (size_t)i * 128 + c * 4) = o;
  }
}

// ---------------- host ----------------

extern "C" void kernel_launch(void* const* d_in, const int* in_sizes, int n_in,
                              void* d_out, int out_size, void* d_ws, size_t ws_size,
                              hipStream_t stream) {
  const float* x = (const float*)d_in[0];
  const int* ei = (const int*)d_in[1];
  const float* W1 = (const float*)d_in[2];
  const float* b1 = (const float*)d_in[3];
  const float* W2 = (const float*)d_in[4];
  const float* b2 = (const float*)d_in[5];
  const float* Wfc = (const float*)d_in[6];
  const float* bfc = (const float*)d_in[7];
  float* out = (float*)d_out;

  int N = in_sizes[0] / 128;
  int E = in_sizes[1] / 2;
  const int* srcp = ei;
  const int* dstp = ei + E;

  char* ws = (char*)d_ws;
  size_t off = 0;
  auto alloc = [&](size_t bytes) -> void* {
    void* p = ws + off;
    off += (bytes + 255) & ~(size_t)255;
    return p;
  };
  float* A = (float*)alloc((size_t)N * 128 * 4);
  float* B = (float*)alloc((size_t)N * 128 * 4);
  int* deg = (int*)alloc((size_t)N * 4);
  int* row_off = (int*)alloc((size_t)(N + 1) * 4);
  int* cursor = (int*)alloc((size_t)N * 4);
  int* blocksums = (int*)alloc(512 * 4);
  float* dinv = (float*)alloc((size_t)N * 4);
  int* edge_src = (int*)alloc((size_t)E * 4);

  hipMemsetAsync(deg, 0, (size_t)N * 4, stream);
  hipMemsetAsync(cursor, 0, (size_t)N * 4, stream);

  int nbE = (E + 255) / 256;
  if (nbE > 2048) nbE = 2048;
  hist_kernel<<<nbE, 256, 0, stream>>>(dstp, deg, E);

  int nbScan = (N + 255) / 256;  // 391 for N=100000, fits scan2's 512 threads
  scan1<<<nbScan, 256, 0, stream>>>(deg, row_off, blocksums, N);
  scan2<<<1, 512, 0, stream>>>(blocksums, nbScan, row_off + N);
  scan3_dinv<<<nbScan, 256, 0, stream>>>(row_off, blocksums, deg, dinv, N);
  scatter_kernel<<<nbE, 256, 0, stream>>>(srcp, dstp, row_off, cursor, edge_src, E);

  int nbG = (N + 127) / 128;
  // layer 1: h1 = x @ W1 ; x2 = relu(agg(h1) + b1)
  gemm_k128<128, false, false><<<nbG, 256, 0, stream>>>(x, W1, nullptr, A, N);
  agg_kernel<<<N, 128, 0, stream>>>(A, row_off, edge_src, dinv, b1, B, N);
  // layer 2
  gemm_k128<128, false, false><<<nbG, 256, 0, stream>>>(B, W2, nullptr, A, N);
  agg_kernel<<<N, 128, 0, stream>>>(A, row_off, edge_src, dinv, b2, B, N);
  // final FC: out = x3 @ Wfc + bfc
  gemm_k128<64, true, false><<<nbG, 256, 0, stream>>>(B, Wfc, bfc, out, N);
}

// Round 5
// 586.393 us; speedup vs baseline: 1.1117x; 1.1117x over previous
//
#include <hip/hip_runtime.h>

typedef unsigned int uint;
typedef unsigned short ushort;

__device__ inline ushort f2bf(float f) {
  uint u = __float_as_uint(f);
  u += 0x7fffu + ((u >> 16) & 1u);   // round-to-nearest-even
  return (ushort)(u >> 16);
}
__device__ inline float bf_lo(uint u) { return __uint_as_float(u << 16); }
__device__ inline float bf_hi(uint u) { return __uint_as_float(u & 0xffff0000u); }

// ---------------- CSR construction ----------------

__global__ __launch_bounds__(256) void hist_kernel(const int* __restrict__ dst,
                                                   int* __restrict__ deg, int nE) {
  int i = blockIdx.x * 256 + threadIdx.x;
  int stride = gridDim.x * 256;
  for (; i < nE; i += stride) atomicAdd(&deg[dst[i]], 1);
}

__global__ __launch_bounds__(256) void scan1(const int* __restrict__ deg,
                                             int* __restrict__ row_off,
                                             int* __restrict__ blocksums, int n) {
  __shared__ int s[256];
  int t = threadIdx.x, i = blockIdx.x * 256 + t;
  int v = (i < n) ? deg[i] : 0;
  s[t] = v;
  __syncthreads();
  for (int off = 1; off < 256; off <<= 1) {
    int x = (t >= off) ? s[t - off] : 0;
    __syncthreads();
    s[t] += x;
    __syncthreads();
  }
  if (i < n) row_off[i] = s[t] - v;        // local exclusive scan
  if (t == 255) blocksums[blockIdx.x] = s[t];
}

__global__ __launch_bounds__(512) void scan2(int* __restrict__ blocksums, int nb,
                                             int* __restrict__ total_out) {
  __shared__ int s[512];
  int t = threadIdx.x;
  int v = (t < nb) ? blocksums[t] : 0;
  s[t] = v;
  __syncthreads();
  for (int off = 1; off < 512; off <<= 1) {
    int x = (t >= off) ? s[t - off] : 0;
    __syncthreads();
    s[t] += x;
    __syncthreads();
  }
  if (t < nb) blocksums[t] = s[t] - v;     // exclusive block offsets
  if (t == 511) *total_out = s[511];       // row_off[N] = nE
}

__global__ __launch_bounds__(256) void scan3_dinv(int* __restrict__ row_off,
                                                  const int* __restrict__ blockoff,
                                                  const int* __restrict__ deg,
                                                  float* __restrict__ dinv, int n) {
  int i = blockIdx.x * 256 + threadIdx.x;
  if (i < n) {
    row_off[i] += blockoff[i >> 8];
    dinv[i] = rsqrtf((float)deg[i] + 1.0f);
  }
}

__global__ __launch_bounds__(256) void scatter_kernel(const int* __restrict__ src,
                                                      const int* __restrict__ dst,
                                                      const int* __restrict__ row_off,
                                                      int* __restrict__ cursor,
                                                      int* __restrict__ edge_src, int nE) {
  int i = blockIdx.x * 256 + threadIdx.x;
  int stride = gridDim.x * 256;
  for (; i < nE; i += stride) {
    int d = dst[i];
    int pos = row_off[d] + atomicAdd(&cursor[d], 1);
    edge_src[pos] = src[i];
  }
}

// ---------------- fp32 GEMM, K=128 fixed ----------------
// OUT_BF16: fp32 accumulate, bf16 (RNE) epilogue write, row stride = COLS bf16.
template <int COLS, bool BIAS, bool RELU, bool OUT_BF16>
__global__ __launch_bounds__(256) void gemm_k128(const float* __restrict__ X,
                                                 const float* __restrict__ W,
                                                 const float* __restrict__ bias,
                                                 void* __restrict__ Yv, int nrows) {
  constexpr int TN = COLS / 16;  // 8 (COLS=128) or 4 (COLS=64)
  __shared__ float Xs[128][33];
  __shared__ float Ws[32 * COLS];
  int tid = threadIdx.x;
  int ty = tid >> 4, tx = tid & 15;
  long row0 = (long)blockIdx.x * 128;

  float acc[8][TN];
#pragma unroll
  for (int r = 0; r < 8; ++r)
#pragma unroll
    for (int j = 0; j < TN; ++j) acc[r][j] = 0.f;

  for (int kt = 0; kt < 4; ++kt) {
#pragma unroll
    for (int l = 0; l < 4; ++l) {
      int idx = tid + l * 256;   // 0..1023 float4 slots
      int r = idx >> 3;          // row in tile
      int k4 = (idx & 7) << 2;   // k offset 0..28
      float4 v = make_float4(0.f, 0.f, 0.f, 0.f);
      long gr = row0 + r;
      if (gr < nrows) v = *(const float4*)(X + gr * 128 + kt * 32 + k4);
      Xs[r][k4 + 0] = v.x;
      Xs[r][k4 + 1] = v.y;
      Xs[r][k4 + 2] = v.z;
      Xs[r][k4 + 3] = v.w;
    }
    constexpr int WF4 = 32 * COLS / 4;
#pragma unroll
    for (int l = 0; l < WF4 / 256; ++l) {
      int idx = tid + l * 256;
      float4 v = *(const float4*)(W + (size_t)kt * 32 * COLS + (size_t)idx * 4);
      *(float4*)(&Ws[idx * 4]) = v;
    }
    __syncthreads();
#pragma unroll
    for (int kk = 0; kk < 32; ++kk) {
      float a[8];
#pragma unroll
      for (int r = 0; r < 8; ++r) a[r] = Xs[ty * 8 + r][kk];
      float b[TN];
      float4 b0 = *(const float4*)(&Ws[kk * COLS + tx * 4]);
      b[0] = b0.x; b[1] = b0.y; b[2] = b0.z; b[3] = b0.w;
      if constexpr (TN == 8) {
        float4 b1 = *(const float4*)(&Ws[kk * COLS + 64 + tx * 4]);
        b[4] = b1.x; b[5] = b1.y; b[6] = b1.z; b[7] = b1.w;
      }
#pragma unroll
      for (int r = 0; r < 8; ++r)
#pragma unroll
        for (int j = 0; j < TN; ++j) acc[r][j] = fmaf(a[r], b[j], acc[r][j]);
    }
    __syncthreads();
  }

  float bv[TN];
  if constexpr (BIAS) {
#pragma unroll
    for (int j = 0; j < TN; ++j) {
      int col = (j < 4) ? tx * 4 + j : 64 + tx * 4 + (j - 4);
      bv[j] = bias[col];
    }
  }
#pragma unroll
  for (int r = 0; r < 8; ++r) {
    long row = row0 + ty * 8 + r;
    if (row < nrows) {
#pragma unroll
      for (int j = 0; j < TN; ++j) {
        if constexpr (BIAS) acc[r][j] += bv[j];
        if constexpr (RELU) acc[r][j] = fmaxf(acc[r][j], 0.f);
      }
      if constexpr (OUT_BF16) {
        ushort* Yb = (ushort*)Yv;
        ushort4 o;
        o.x = f2bf(acc[r][0]); o.y = f2bf(acc[r][1]);
        o.z = f2bf(acc[r][2]); o.w = f2bf(acc[r][3]);
        *(ushort4*)(Yb + (size_t)row * COLS + tx * 4) = o;
        if constexpr (TN == 8) {
          ushort4 o2;
          o2.x = f2bf(acc[r][4]); o2.y = f2bf(acc[r][5]);
          o2.z = f2bf(acc[r][6]); o2.w = f2bf(acc[r][7]);
          *(ushort4*)(Yb + (size_t)row * COLS + 64 + tx * 4) = o2;
        }
      } else {
        float* Y = (float*)Yv;
        float4 o = make_float4(acc[r][0], acc[r][1], acc[r][2], acc[r][3]);
        *(float4*)(Y + (size_t)row * COLS + tx * 4) = o;
        if constexpr (TN == 8) {
          float4 o2 = make_float4(acc[r][4], acc[r][5], acc[r][6], acc[r][7]);
          *(float4*)(Y + (size_t)row * COLS + 64 + tx * 4) = o2;
        }
      }
    }
  }
}

// ---------------- neighbor aggregation (one node per block) ----------------
// H is bf16 [n][128] (256 B/row). 128 threads = 8 edge-groups x 16 lanes.
// Lane c covers feats [8c, 8c+8) via one uint4 (16 B) per edge. fp32 accum.
// out[i][:] = relu( sum_e H[src_e]*dinv[src]*dinv[i] + H[i]*dinv[i]^2 + b )
__global__ __launch_bounds__(128) void agg_kernel(const ushort* __restrict__ H,
                                                  const int* __restrict__ row_off,
                                                  const int* __restrict__ edge_src,
                                                  const float* __restrict__ dinv,
                                                  const float* __restrict__ bias,
                                                  float* __restrict__ Out, int n) {
  int i = blockIdx.x;
  int t = threadIdx.x;
  int g = t >> 4;        // edge group 0..7
  int c = t & 15;        // feature block: feats [8c, 8c+8)
  float di = dinv[i];
  int beg = row_off[i], end = row_off[i + 1];

  float acc[8];
#pragma unroll
  for (int k = 0; k < 8; ++k) acc[k] = 0.f;

  __shared__ int sidx[128];
  __shared__ float swt[128];
  for (int base = beg; base < end; base += 128) {
    int cnt = min(128, end - base);
    if (t < cnt) {
      int s = edge_src[base + t];
      sidx[t] = s;
      swt[t] = dinv[s] * di;
    }
    __syncthreads();
#pragma unroll 2
    for (int j = g; j < cnt; j += 8) {
      uint4 q = *(const uint4*)(H + (size_t)sidx[j] * 128 + c * 8);
      float w = swt[j];
      acc[0] = fmaf(bf_lo(q.x), w, acc[0]);
      acc[1] = fmaf(bf_hi(q.x), w, acc[1]);
      acc[2] = fmaf(bf_lo(q.y), w, acc[2]);
      acc[3] = fmaf(bf_hi(q.y), w, acc[3]);
      acc[4] = fmaf(bf_lo(q.z), w, acc[4]);
      acc[5] = fmaf(bf_hi(q.z), w, acc[5]);
      acc[6] = fmaf(bf_lo(q.w), w, acc[6]);
      acc[7] = fmaf(bf_hi(q.w), w, acc[7]);
    }
    __syncthreads();
  }

  // reduce 8 groups: within each 64-lane wave fold 4 groups, then cross-wave via LDS
#pragma unroll
  for (int k = 0; k < 8; ++k) acc[k] += __shfl_down(acc[k], 32);
#pragma unroll
  for (int k = 0; k < 8; ++k) acc[k] += __shfl_down(acc[k], 16);

  __shared__ float red[16][8];
  if (t >= 64 && t < 80) {
#pragma unroll
    for (int k = 0; k < 8; ++k) red[c][k] = acc[k];
  }
  __syncthreads();
  if (t < 16) {
    uint4 q = *(const uint4*)(H + (size_t)i * 128 + c * 8);
    float sw = di * di;
    float self_[8] = {bf_lo(q.x), bf_hi(q.x), bf_lo(q.y), bf_hi(q.y),
                      bf_lo(q.z), bf_hi(q.z), bf_lo(q.w), bf_hi(q.w)};
    float4 bA = *(const float4*)(bias + c * 8);
    float4 bB = *(const float4*)(bias + c * 8 + 4);
    float o[8];
#pragma unroll
    for (int k = 0; k < 8; ++k) o[k] = acc[k] + red[c][k] + self_[k] * sw;
    o[0] += bA.x; o[1] += bA.y; o[2] += bA.z; o[3] += bA.w;
    o[4] += bB.x; o[5] += bB.y; o[6] += bB.z; o[7] += bB.w;
#pragma unroll
    for (int k = 0; k < 8; ++k) o[k] = fmaxf(o[k], 0.f);
    *(float4*)(Out + (size_t)i * 128 + c * 8) = make_float4(o[0], o[1], o[2], o[3]);
    *(float4*)(Out + (size_t)i * 128 + c * 8 + 4) = make_float4(o[4], o[5], o[6], o[7]);
  }
}

// ---------------- host ----------------

extern "C" void kernel_launch(void* const* d_in, const int* in_sizes, int n_in,
                              void* d_out, int out_size, void* d_ws, size_t ws_size,
                              hipStream_t stream) {
  const float* x = (const float*)d_in[0];
  const int* ei = (const int*)d_in[1];
  const float* W1 = (const float*)d_in[2];
  const float* b1 = (const float*)d_in[3];
  const float* W2 = (const float*)d_in[4];
  const float* b2 = (const float*)d_in[5];
  const float* Wfc = (const float*)d_in[6];
  const float* bfc = (const float*)d_in[7];
  float* out = (float*)d_out;

  int N = in_sizes[0] / 128;
  int E = in_sizes[1] / 2;
  const int* srcp = ei;
  const int* dstp = ei + E;

  char* ws = (char*)d_ws;
  size_t off = 0;
  auto alloc = [&](size_t bytes) -> void* {
    void* p = ws + off;
    off += (bytes + 255) & ~(size_t)255;
    return p;
  };
  ushort* Hb = (ushort*)alloc((size_t)N * 128 * 2);   // bf16 post-GEMM features
  float* X2 = (float*)alloc((size_t)N * 128 * 4);     // fp32 post-agg features
  int* deg = (int*)alloc((size_t)N * 4);
  int* row_off = (int*)alloc((size_t)(N + 1) * 4);
  int* cursor = (int*)alloc((size_t)N * 4);
  int* blocksums = (int*)alloc(512 * 4);
  float* dinv = (float*)alloc((size_t)N * 4);
  int* edge_src = (int*)alloc((size_t)E * 4);

  hipMemsetAsync(deg, 0, (size_t)N * 4, stream);
  hipMemsetAsync(cursor, 0, (size_t)N * 4, stream);

  int nbE = (E + 255) / 256;
  if (nbE > 2048) nbE = 2048;
  hist_kernel<<<nbE, 256, 0, stream>>>(dstp, deg, E);

  int nbScan = (N + 255) / 256;  // 391 for N=100000, fits scan2's 512 threads
  scan1<<<nbScan, 256, 0, stream>>>(deg, row_off, blocksums, N);
  scan2<<<1, 512, 0, stream>>>(blocksums, nbScan, row_off + N);
  scan3_dinv<<<nbScan, 256, 0, stream>>>(row_off, blocksums, deg, dinv, N);
  scatter_kernel<<<nbE, 256, 0, stream>>>(srcp, dstp, row_off, cursor, edge_src, E);

  int nbG = (N + 127) / 128;
  // layer 1: h1 = bf16(x @ W1) ; x2 = relu(agg(h1) + b1)
  gemm_k128<128, false, false, true><<<nbG, 256, 0, stream>>>(x, W1, nullptr, Hb, N);
  agg_kernel<<<N, 128, 0, stream>>>(Hb, row_off, edge_src, dinv, b1, X2, N);
  // layer 2
  gemm_k128<128, false, false, true><<<nbG, 256, 0, stream>>>(X2, W2, nullptr, Hb, N);
  agg_kernel<<<N, 128, 0, stream>>>(Hb, row_off, edge_src, dinv, b2, X2, N);
  // final FC: out = x3 @ Wfc + bfc
  gemm_k128<64, true, false, false><<<nbG, 256, 0, stream>>>(X2, Wfc, bfc, out, N);
}

// Round 6
// 565.939 us; speedup vs baseline: 1.1519x; 1.0361x over previous
//
#include <hip/hip_runtime.h>

typedef unsigned int uint;
typedef unsigned short ushort;

__device__ inline ushort f2bf(float f) {
  uint u = __float_as_uint(f);
  u += 0x7fffu + ((u >> 16) & 1u);   // round-to-nearest-even
  return (ushort)(u >> 16);
}
__device__ inline float bf_lo(uint u) { return __uint_as_float(u << 16); }
__device__ inline float bf_hi(uint u) { return __uint_as_float(u & 0xffff0000u); }

// ---------------- CSR construction ----------------

__global__ __launch_bounds__(256) void hist_kernel(const int* __restrict__ dst,
                                                   int* __restrict__ deg, int nE) {
  int i = blockIdx.x * 256 + threadIdx.x;
  int stride = gridDim.x * 256;
  for (; i < nE; i += stride) atomicAdd(&deg[dst[i]], 1);
}

__global__ __launch_bounds__(256) void scan1(const int* __restrict__ deg,
                                             int* __restrict__ row_off,
                                             int* __restrict__ blocksums, int n) {
  __shared__ int s[256];
  int t = threadIdx.x, i = blockIdx.x * 256 + t;
  int v = (i < n) ? deg[i] : 0;
  s[t] = v;
  __syncthreads();
  for (int off = 1; off < 256; off <<= 1) {
    int x = (t >= off) ? s[t - off] : 0;
    __syncthreads();
    s[t] += x;
    __syncthreads();
  }
  if (i < n) row_off[i] = s[t] - v;        // local exclusive scan
  if (t == 255) blocksums[blockIdx.x] = s[t];
}

__global__ __launch_bounds__(512) void scan2(int* __restrict__ blocksums, int nb,
                                             int* __restrict__ total_out) {
  __shared__ int s[512];
  int t = threadIdx.x;
  int v = (t < nb) ? blocksums[t] : 0;
  s[t] = v;
  __syncthreads();
  for (int off = 1; off < 512; off <<= 1) {
    int x = (t >= off) ? s[t - off] : 0;
    __syncthreads();
    s[t] += x;
    __syncthreads();
  }
  if (t < nb) blocksums[t] = s[t] - v;     // exclusive block offsets
  if (t == 511) *total_out = s[511];       // row_off[N] = nE
}

__global__ __launch_bounds__(256) void scan3_dinv(int* __restrict__ row_off,
                                                  const int* __restrict__ blockoff,
                                                  const int* __restrict__ deg,
                                                  float* __restrict__ dinv, int n) {
  int i = blockIdx.x * 256 + threadIdx.x;
  if (i < n) {
    row_off[i] += blockoff[i >> 8];
    dinv[i] = rsqrtf((float)deg[i] + 1.0f);
  }
}

// Windowed counting-sort scatter: pass handles dst in [lo, hi) only, so the
// write region edge_src[row_off[lo]..row_off[hi]) is a contiguous ~1.6 MB
// span that stays L2-resident while lines fill fully (16 x 4B per line).
__global__ __launch_bounds__(256) void scatter_kernel(const int* __restrict__ src,
                                                      const int* __restrict__ dst,
                                                      const int* __restrict__ row_off,
                                                      int* __restrict__ cursor,
                                                      int* __restrict__ edge_src, int nE,
                                                      int lo, int hi) {
  int i = blockIdx.x * 256 + threadIdx.x;
  int stride = gridDim.x * 256;
  for (; i < nE; i += stride) {
    int d = dst[i];
    if (d >= lo && d < hi) {
      int pos = row_off[d] + atomicAdd(&cursor[d], 1);
      edge_src[pos] = src[i];
    }
  }
}

// ---------------- fp32 GEMM, K=128 fixed ----------------
// OUT_BF16: fp32 accumulate, bf16 (RNE) epilogue write, row stride = COLS bf16.
template <int COLS, bool BIAS, bool RELU, bool OUT_BF16>
__global__ __launch_bounds__(256) void gemm_k128(const float* __restrict__ X,
                                                 const float* __restrict__ W,
                                                 const float* __restrict__ bias,
                                                 void* __restrict__ Yv, int nrows) {
  constexpr int TN = COLS / 16;  // 8 (COLS=128) or 4 (COLS=64)
  __shared__ float Xs[128][33];
  __shared__ float Ws[32 * COLS];
  int tid = threadIdx.x;
  int ty = tid >> 4, tx = tid & 15;
  long row0 = (long)blockIdx.x * 128;

  float acc[8][TN];
#pragma unroll
  for (int r = 0; r < 8; ++r)
#pragma unroll
    for (int j = 0; j < TN; ++j) acc[r][j] = 0.f;

  for (int kt = 0; kt < 4; ++kt) {
#pragma unroll
    for (int l = 0; l < 4; ++l) {
      int idx = tid + l * 256;   // 0..1023 float4 slots
      int r = idx >> 3;          // row in tile
      int k4 = (idx & 7) << 2;   // k offset 0..28
      float4 v = make_float4(0.f, 0.f, 0.f, 0.f);
      long gr = row0 + r;
      if (gr < nrows) v = *(const float4*)(X + gr * 128 + kt * 32 + k4);
      Xs[r][k4 + 0] = v.x;
      Xs[r][k4 + 1] = v.y;
      Xs[r][k4 + 2] = v.z;
      Xs[r][k4 + 3] = v.w;
    }
    constexpr int WF4 = 32 * COLS / 4;
#pragma unroll
    for (int l = 0; l < WF4 / 256; ++l) {
      int idx = tid + l * 256;
      float4 v = *(const float4*)(W + (size_t)kt * 32 * COLS + (size_t)idx * 4);
      *(float4*)(&Ws[idx * 4]) = v;
    }
    __syncthreads();
#pragma unroll
    for (int kk = 0; kk < 32; ++kk) {
      float a[8];
#pragma unroll
      for (int r = 0; r < 8; ++r) a[r] = Xs[ty * 8 + r][kk];
      float b[TN];
      float4 b0 = *(const float4*)(&Ws[kk * COLS + tx * 4]);
      b[0] = b0.x; b[1] = b0.y; b[2] = b0.z; b[3] = b0.w;
      if constexpr (TN == 8) {
        float4 b1 = *(const float4*)(&Ws[kk * COLS + 64 + tx * 4]);
        b[4] = b1.x; b[5] = b1.y; b[6] = b1.z; b[7] = b1.w;
      }
#pragma unroll
      for (int r = 0; r < 8; ++r)
#pragma unroll
        for (int j = 0; j < TN; ++j) acc[r][j] = fmaf(a[r], b[j], acc[r][j]);
    }
    __syncthreads();
  }

  float bv[TN];
  if constexpr (BIAS) {
#pragma unroll
    for (int j = 0; j < TN; ++j) {
      int col = (j < 4) ? tx * 4 + j : 64 + tx * 4 + (j - 4);
      bv[j] = bias[col];
    }
  }
#pragma unroll
  for (int r = 0; r < 8; ++r) {
    long row = row0 + ty * 8 + r;
    if (row < nrows) {
#pragma unroll
      for (int j = 0; j < TN; ++j) {
        if constexpr (BIAS) acc[r][j] += bv[j];
        if constexpr (RELU) acc[r][j] = fmaxf(acc[r][j], 0.f);
      }
      if constexpr (OUT_BF16) {
        ushort* Yb = (ushort*)Yv;
        ushort4 o;
        o.x = f2bf(acc[r][0]); o.y = f2bf(acc[r][1]);
        o.z = f2bf(acc[r][2]); o.w = f2bf(acc[r][3]);
        *(ushort4*)(Yb + (size_t)row * COLS + tx * 4) = o;
        if constexpr (TN == 8) {
          ushort4 o2;
          o2.x = f2bf(acc[r][4]); o2.y = f2bf(acc[r][5]);
          o2.z = f2bf(acc[r][6]); o2.w = f2bf(acc[r][7]);
          *(ushort4*)(Yb + (size_t)row * COLS + 64 + tx * 4) = o2;
        }
      } else {
        float* Y = (float*)Yv;
        float4 o = make_float4(acc[r][0], acc[r][1], acc[r][2], acc[r][3]);
        *(float4*)(Y + (size_t)row * COLS + tx * 4) = o;
        if constexpr (TN == 8) {
          float4 o2 = make_float4(acc[r][4], acc[r][5], acc[r][6], acc[r][7]);
          *(float4*)(Y + (size_t)row * COLS + 64 + tx * 4) = o2;
        }
      }
    }
  }
}

// ---------------- neighbor aggregation (one node per block) ----------------
// H is bf16 [n][128] (256 B/row). 128 threads = 8 edge-groups x 16 lanes.
// Lane c covers feats [8c, 8c+8) via one uint4 (16 B) per edge. fp32 accum.
// out[i][:] = relu( sum_e H[src_e]*dinv[src]*dinv[i] + H[i]*dinv[i]^2 + b )
__global__ __launch_bounds__(128) void agg_kernel(const ushort* __restrict__ H,
                                                  const int* __restrict__ row_off,
                                                  const int* __restrict__ edge_src,
                                                  const float* __restrict__ dinv,
                                                  const float* __restrict__ bias,
                                                  float* __restrict__ Out, int n) {
  int i = blockIdx.x;
  int t = threadIdx.x;
  int g = t >> 4;        // edge group 0..7
  int c = t & 15;        // feature block: feats [8c, 8c+8)
  float di = dinv[i];
  int beg = row_off[i], end = row_off[i + 1];

  float acc[8];
#pragma unroll
  for (int k = 0; k < 8; ++k) acc[k] = 0.f;

  __shared__ int sidx[128];
  __shared__ float swt[128];
  for (int base = beg; base < end; base += 128) {
    int cnt = min(128, end - base);
    if (t < cnt) {
      int s = edge_src[base + t];
      sidx[t] = s;
      swt[t] = dinv[s] * di;
    }
    __syncthreads();
#pragma unroll 2
    for (int j = g; j < cnt; j += 8) {
      uint4 q = *(const uint4*)(H + (size_t)sidx[j] * 128 + c * 8);
      float w = swt[j];
      acc[0] = fmaf(bf_lo(q.x), w, acc[0]);
      acc[1] = fmaf(bf_hi(q.x), w, acc[1]);
      acc[2] = fmaf(bf_lo(q.y), w, acc[2]);
      acc[3] = fmaf(bf_hi(q.y), w, acc[3]);
      acc[4] = fmaf(bf_lo(q.z), w, acc[4]);
      acc[5] = fmaf(bf_hi(q.z), w, acc[5]);
      acc[6] = fmaf(bf_lo(q.w), w, acc[6]);
      acc[7] = fmaf(bf_hi(q.w), w, acc[7]);
    }
    __syncthreads();
  }

  // reduce 8 groups: within each 64-lane wave fold 4 groups, then cross-wave via LDS
#pragma unroll
  for (int k = 0; k < 8; ++k) acc[k] += __shfl_down(acc[k], 32);
#pragma unroll
  for (int k = 0; k < 8; ++k) acc[k] += __shfl_down(acc[k], 16);

  __shared__ float red[16][8];
  if (t >= 64 && t < 80) {
#pragma unroll
    for (int k = 0; k < 8; ++k) red[c][k] = acc[k];
  }
  __syncthreads();
  if (t < 16) {
    uint4 q = *(const uint4*)(H + (size_t)i * 128 + c * 8);
    float sw = di * di;
    float self_[8] = {bf_lo(q.x), bf_hi(q.x), bf_lo(q.y), bf_hi(q.y),
                      bf_lo(q.z), bf_hi(q.z), bf_lo(q.w), bf_hi(q.w)};
    float4 bA = *(const float4*)(bias + c * 8);
    float4 bB = *(const float4*)(bias + c * 8 + 4);
    float o[8];
#pragma unroll
    for (int k = 0; k < 8; ++k) o[k] = acc[k] + red[c][k] + self_[k] * sw;
    o[0] += bA.x; o[1] += bA.y; o[2] += bA.z; o[3] += bA.w;
    o[4] += bB.x; o[5] += bB.y; o[6] += bB.z; o[7] += bB.w;
#pragma unroll
    for (int k = 0; k < 8; ++k) o[k] = fmaxf(o[k], 0.f);
    *(float4*)(Out + (size_t)i * 128 + c * 8) = make_float4(o[0], o[1], o[2], o[3]);
    *(float4*)(Out + (size_t)i * 128 + c * 8 + 4) = make_float4(o[4], o[5], o[6], o[7]);
  }
}

// ---------------- host ----------------

extern "C" void kernel_launch(void* const* d_in, const int* in_sizes, int n_in,
                              void* d_out, int out_size, void* d_ws, size_t ws_size,
                              hipStream_t stream) {
  const float* x = (const float*)d_in[0];
  const int* ei = (const int*)d_in[1];
  const float* W1 = (const float*)d_in[2];
  const float* b1 = (const float*)d_in[3];
  const float* W2 = (const float*)d_in[4];
  const float* b2 = (const float*)d_in[5];
  const float* Wfc = (const float*)d_in[6];
  const float* bfc = (const float*)d_in[7];
  float* out = (float*)d_out;

  int N = in_sizes[0] / 128;
  int E = in_sizes[1] / 2;
  const int* srcp = ei;
  const int* dstp = ei + E;

  char* ws = (char*)d_ws;
  size_t off = 0;
  auto alloc = [&](size_t bytes) -> void* {
    void* p = ws + off;
    off += (bytes + 255) & ~(size_t)255;
    return p;
  };
  ushort* Hb = (ushort*)alloc((size_t)N * 128 * 2);   // bf16 post-GEMM features
  float* X2 = (float*)alloc((size_t)N * 128 * 4);     // fp32 post-agg features
  int* deg = (int*)alloc((size_t)N * 4);
  int* row_off = (int*)alloc((size_t)(N + 1) * 4);
  int* cursor = (int*)alloc((size_t)N * 4);
  int* blocksums = (int*)alloc(512 * 4);
  float* dinv = (float*)alloc((size_t)N * 4);
  int* edge_src = (int*)alloc((size_t)E * 4);

  hipMemsetAsync(deg, 0, (size_t)N * 4, stream);
  hipMemsetAsync(cursor, 0, (size_t)N * 4, stream);

  int nbE = (E + 255) / 256;
  if (nbE > 2048) nbE = 2048;
  hist_kernel<<<nbE, 256, 0, stream>>>(dstp, deg, E);

  int nbScan = (N + 255) / 256;  // 391 for N=100000, fits scan2's 512 threads
  scan1<<<nbScan, 256, 0, stream>>>(deg, row_off, blocksums, N);
  scan2<<<1, 512, 0, stream>>>(blocksums, nbScan, row_off + N);
  scan3_dinv<<<nbScan, 256, 0, stream>>>(row_off, blocksums, deg, dinv, N);

  // 4-pass windowed counting-sort scatter: each pass's write region is a
  // contiguous ~E/4*4B span -> L2-resident, lines fill before eviction.
  constexpr int NPASS = 4;
  int wsz = (N + NPASS - 1) / NPASS;
  for (int w = 0; w < NPASS; ++w) {
    int lo = w * wsz;
    int hi = min(N, lo + wsz);
    scatter_kernel<<<nbE, 256, 0, stream>>>(srcp, dstp, row_off, cursor, edge_src, E, lo, hi);
  }

  int nbG = (N + 127) / 128;
  // layer 1: h1 = bf16(x @ W1) ; x2 = relu(agg(h1) + b1)
  gemm_k128<128, false, false, true><<<nbG, 256, 0, stream>>>(x, W1, nullptr, Hb, N);
  agg_kernel<<<N, 128, 0, stream>>>(Hb, row_off, edge_src, dinv, b1, X2, N);
  // layer 2
  gemm_k128<128, false, false, true><<<nbG, 256, 0, stream>>>(X2, W2, nullptr, Hb, N);
  agg_kernel<<<N, 128, 0, stream>>>(Hb, row_off, edge_src, dinv, b2, X2, N);
  // final FC: out = x3 @ Wfc + bfc
  gemm_k128<64, true, false, false><<<nbG, 256, 0, stream>>>(X2, Wfc, bfc, out, N);
}